// Round 9
// baseline (401.993 us; speedup 1.0000x reference)
//
#include <hip/hip_runtime.h>
#include <hip/hip_bf16.h>

// Problem constants
#define B_ 32
#define T_ 64
#define E_ 512
#define H_ 512
#define V_ 10000
#define G4 2048   // 4*H

#define SENT 0xFFFFFFFFFFFFFFFFull   // 4x bf16 NaN — impossible as h output

using bf16x8 = __attribute__((ext_vector_type(8))) short;  // 8 bf16 in 4 VGPRs
using f32x4  = __attribute__((ext_vector_type(4))) float;

__device__ inline f32x4 mfma16(bf16x8 a, bf16x8 b, f32x4 c) {
  return __builtin_amdgcn_mfma_f32_16x16x32_bf16(a, b, c, 0, 0, 0);
}

// fp32 -> bf16 round-to-nearest-even, stored as short
__device__ inline short f2bf(float x) {
  unsigned u = __builtin_bit_cast(unsigned, x);
  u = (u + 0x7fffu + ((u >> 16) & 1u)) >> 16;
  return (short)u;
}

// fast transcendental pointwise (bf16-output accuracy is the bar)
__device__ inline float fsigm(float x) {
  return __builtin_amdgcn_rcpf(1.f + __builtin_amdgcn_exp2f(-1.442695040888963f * x));
}
__device__ inline float ftanh(float x) {
  return 1.f - 2.f * __builtin_amdgcn_rcpf(1.f + __builtin_amdgcn_exp2f(2.885390081777927f * x));
}

// Swizzled 16B LDS read: row stride 1024B, byte ^= (row&7)<<4 kills the
// 16-way bank conflict of the row-major [*][512] bf16 layout (guide G4).
__device__ inline bf16x8 lds_ld16B(const short* base, int row, int col) {
  int byte = (row << 10) + (col << 1);
  byte ^= (row & 7) << 4;
  return *(const bf16x8*)((const char*)base + byte);
}

// ---------------- fused prep kernel ----------------
// One grid-stride kernel: cast W_ih, W_hh, fc_W to bf16; bsum; build xs;
// fill hs with the sentinel (8B words).

#define N1 (G4 * E_)                 // W_ih
#define N2 (N1 + G4 * H_)            // W_hh
#define N3 (N2 + V_ * H_)            // fc_W
#define N4 (N3 + G4)                 // bsum
#define N5 (N4 + T_ * B_ * E_)       // xs
#define N6 (N5 + T_ * B_ * H_ / 4)   // hs sentinel (u64 words)

__global__ void prep_kernel(const float* __restrict__ W_ih, const float* __restrict__ W_hh,
                            const float* __restrict__ fc_W, const float* __restrict__ b_ih,
                            const float* __restrict__ b_hh, const float* __restrict__ features,
                            const int* __restrict__ captions, const float* __restrict__ embed,
                            short* __restrict__ wih_bf, short* __restrict__ whh_bf,
                            short* __restrict__ fcw_bf, float* __restrict__ bsum,
                            short* __restrict__ xs, unsigned long long* __restrict__ hs64) {
  int i = blockIdx.x * blockDim.x + threadIdx.x;
  int stride = gridDim.x * blockDim.x;
  for (; i < N6; i += stride) {
    if (i < N1) {
      wih_bf[i] = f2bf(W_ih[i]);
    } else if (i < N2) {
      int j = i - N1;
      whh_bf[j] = f2bf(W_hh[j]);
    } else if (i < N3) {
      int j = i - N2;
      fcw_bf[j] = f2bf(fc_W[j]);
    } else if (i < N4) {
      int j = i - N3;
      bsum[j] = b_ih[j] + b_hh[j];
    } else if (i < N5) {
      int j = i - N4;                 // [t][b][e]
      int t = j / (B_ * E_);
      int r = j - t * (B_ * E_);
      int b = r >> 9;
      int e = r & 511;
      float v;
      if (t == 0) v = features[b * E_ + e];
      else        v = embed[captions[b * T_ + (t - 1)] * E_ + e];
      xs[j] = f2bf(v);
    } else {
      hs64[i - N5] = SENT;
    }
  }
}

// ---------------- Gx GEMM ----------------
// Computes xs @ W_ih^T + (b_ih+b_hh), M=2048 (t*32+b), N=2048 (g*512+hc), K=512.
// OUTPUT LAYOUT: Gxt[t][g][b][hc] = [((t*4+g)*32+b)*512 + hc].

__global__ __launch_bounds__(256) void gemm_gx_kernel(const short* __restrict__ A,
                                                      const short* __restrict__ W,
                                                      const float* __restrict__ bias,
                                                      float* __restrict__ C) {
  const int lane = threadIdx.x & 63;
  const int wv   = threadIdx.x >> 6;
  const int m0 = blockIdx.y * 64 + (wv >> 1) * 32;
  const int n0 = blockIdx.x * 64 + (wv & 1) * 32;
  const int lr = lane & 15;
  const int ko = (lane >> 4) << 3;
  f32x4 acc[2][2] = {};
  const short* Ap = A + (m0 + lr) * 512 + ko;
  const short* Wp = W + (n0 + lr) * 512 + ko;
#pragma unroll
  for (int k = 0; k < 512; k += 32) {
    bf16x8 a0 = *(const bf16x8*)(Ap + k);
    bf16x8 a1 = *(const bf16x8*)(Ap + 16 * 512 + k);
    bf16x8 b0 = *(const bf16x8*)(Wp + k);
    bf16x8 b1 = *(const bf16x8*)(Wp + 16 * 512 + k);
    acc[0][0] = mfma16(a0, b0, acc[0][0]);
    acc[0][1] = mfma16(a0, b1, acc[0][1]);
    acc[1][0] = mfma16(a1, b0, acc[1][0]);
    acc[1][1] = mfma16(a1, b1, acc[1][1]);
  }
  const int cr = (lane >> 4) * 4, cc = lane & 15;
#pragma unroll
  for (int mi = 0; mi < 2; ++mi)
#pragma unroll
    for (int ni = 0; ni < 2; ++ni)
#pragma unroll
      for (int j = 0; j < 4; ++j) {
        int row = m0 + mi * 16 + cr + j;   // t*32 + b
        int col = n0 + ni * 16 + cc;       // g*512 + hc
        int tt = row >> 5, bb = row & 31;
        int g  = col >> 9, hc = col & 511;
        C[(size_t)((tt * 4 + g) * 32 + bb) * 512 + hc] = acc[mi][ni][j] + bias[col];
      }
}

// ---------------- persistent LSTM recurrence, sentinel-poll handoff ----------------
// 64 blocks x 64 threads: block = (bg, slot) owns batch group bg (16 samples)
// and h columns [slot*16, slot*16+16). NO FLAGS: hs is pre-filled with the
// 8B sentinel 0xFFFF... (bf16 NaN x4 — unreachable since h in (-1,1));
// producers' 8B agent-scope atomic stores atomically replace whole words;
// consumers poll the exact data words they need (agent loads = L2-bypass,
// fresh) until != sentinel. This merges data+signal: no producer drain, no
// flag round-trip. Consumption pipelined in 4 K-chunks of 128 cols.
// Hang-impossible: producers always store; a non-sentinel word is final.

__global__ __launch_bounds__(64) void lstm_kernel(const short* __restrict__ Whh,
                                                  const float* __restrict__ Gx,
                                                  short* __restrict__ hs) {  // [T][B][H] bf16
  __shared__ short Wlds[64 * 512];    // 64 KB, swizzled
  const int lane = threadIdx.x;       // 0..63
  const int blk  = blockIdx.x;        // 0..63
  const int bg   = blk >> 5;          // batch group 0/1
  const int slot = blk & 31;          // h-column slot
  const int hc0  = slot * 16;

  // stage W_hh slice (swizzled): logical row gc = g*16+c  <-  Whh row g*512+hc0+c
  for (int i = lane * 8; i < 64 * 512; i += 64 * 8) {
    int gc = i >> 9;
    int k  = i & 511;
    int g  = gc >> 4, c = gc & 15;
    bf16x8 v = *(const bf16x8*)&Whh[(g * 512 + hc0 + c) * 512 + k];
    int byte = (i * 2) ^ ((gc & 7) << 4);
    *(bf16x8*)((char*)Wlds + byte) = v;
  }
  __syncthreads();

  const int lr  = lane & 15;
  const int ko  = (lane >> 4) << 3;   // k-offset within 32-chunk (0,8,16,24)
  const int cr  = (lane >> 4) << 2;   // hcol-rel base (0,4,8,12)
  const int cc  = lane & 15;
  const int bat = bg * 16 + cc;       // global batch of this lane's cells
  const int hrow = bg * 16 + lr;      // h row this lane loads for B-frag

  // Gxt[t][g][bat][hc0+cr ..+4): one float4 per gate
  const float* gbase = Gx + (size_t)bat * 512 + hc0 + cr;
  float4 gx0 = *(const float4*)(gbase + 0 * 32 * 512);
  float4 gx1 = *(const float4*)(gbase + 1 * 32 * 512);
  float4 gx2 = *(const float4*)(gbase + 2 * 32 * 512);
  float4 gx3 = *(const float4*)(gbase + 3 * 32 * 512);

  float cst[4] = {0.f, 0.f, 0.f, 0.f};   // cell state, static-indexed only

  for (int t = 0; t < T_; ++t) {
    f32x4 a0 = {}, a1 = {}, a2 = {}, a3 = {};   // acc per gate (i,f,g,o)
    if (t > 0) {
      // h row slice this lane consumes: row hrow, u64 words of hs[t-1]
      const unsigned long long* hp =
          (const unsigned long long*)(hs + (size_t)(t - 1) * (B_ * H_)) + hrow * 128;
      // 4 K-chunks of 128 cols: poll 8 words (chunks kk=c*4..c*4+3), then MFMA
#pragma unroll
      for (int c = 0; c < 4; ++c) {
        const int wb = c * 32 + (ko >> 2);   // word base for this lane, chunk c
        unsigned long long w0, w1, w2, w3, w4, w5, w6, w7;
        for (;;) {
          w0 = __hip_atomic_load(hp + wb +  0, __ATOMIC_RELAXED, __HIP_MEMORY_SCOPE_AGENT);
          w1 = __hip_atomic_load(hp + wb +  1, __ATOMIC_RELAXED, __HIP_MEMORY_SCOPE_AGENT);
          w2 = __hip_atomic_load(hp + wb +  8, __ATOMIC_RELAXED, __HIP_MEMORY_SCOPE_AGENT);
          w3 = __hip_atomic_load(hp + wb +  9, __ATOMIC_RELAXED, __HIP_MEMORY_SCOPE_AGENT);
          w4 = __hip_atomic_load(hp + wb + 16, __ATOMIC_RELAXED, __HIP_MEMORY_SCOPE_AGENT);
          w5 = __hip_atomic_load(hp + wb + 17, __ATOMIC_RELAXED, __HIP_MEMORY_SCOPE_AGENT);
          w6 = __hip_atomic_load(hp + wb + 24, __ATOMIC_RELAXED, __HIP_MEMORY_SCOPE_AGENT);
          w7 = __hip_atomic_load(hp + wb + 25, __ATOMIC_RELAXED, __HIP_MEMORY_SCOPE_AGENT);
          if ((w0 != SENT) & (w1 != SENT) & (w2 != SENT) & (w3 != SENT) &
              (w4 != SENT) & (w5 != SENT) & (w6 != SENT) & (w7 != SENT)) break;
        }
        union { unsigned long long q[2]; bf16x8 v; } hb;
        const int kk0 = c * 4 * 32;   // col base of chunk c
#pragma unroll
        for (int j = 0; j < 4; ++j) {
          switch (j) {   // static pairs -> registers, no scratch
            case 0: hb.q[0] = w0; hb.q[1] = w1; break;
            case 1: hb.q[0] = w2; hb.q[1] = w3; break;
            case 2: hb.q[0] = w4; hb.q[1] = w5; break;
            default: hb.q[0] = w6; hb.q[1] = w7; break;
          }
          const int kc = kk0 + j * 32 + ko;
          bf16x8 wA0 = lds_ld16B(Wlds,      lr, kc);
          bf16x8 wA1 = lds_ld16B(Wlds, 16 + lr, kc);
          bf16x8 wA2 = lds_ld16B(Wlds, 32 + lr, kc);
          bf16x8 wA3 = lds_ld16B(Wlds, 48 + lr, kc);
          a0 = mfma16(wA0, hb.v, a0);
          a1 = mfma16(wA1, hb.v, a1);
          a2 = mfma16(wA2, hb.v, a2);
          a3 = mfma16(wA3, hb.v, a3);
        }
      }
    }
    // pointwise LSTM cell, fully in-register (cols hc0+cr..+3, batch bat)
    unsigned long long hpack = 0;
#pragma unroll
    for (int j = 0; j < 4; ++j) {
      float iv = fsigm(a0[j] + ((const float*)&gx0)[j]);
      float fv = fsigm(a1[j] + ((const float*)&gx1)[j]);
      float gv = ftanh(a2[j] + ((const float*)&gx2)[j]);
      float ov = fsigm(a3[j] + ((const float*)&gx3)[j]);
      float cv = fv * cst[j] + iv * gv;
      cst[j] = cv;
      float hv = ov * ftanh(cv);
      hpack |= (unsigned long long)(unsigned short)f2bf(hv) << (16 * j);
    }
    // one 8B agent-scope atomic store (atomic word replace; IS the signal)
    __hip_atomic_store(
        (unsigned long long*)(hs + (size_t)t * (B_ * H_) + bat * 512 + hc0 + cr),
        hpack, __ATOMIC_RELAXED, __HIP_MEMORY_SCOPE_AGENT);
    // prefetch Gx for t+1 (latency hides under next step's data poll)
    if (t < T_ - 1) {
      const float* g0 = gbase + (size_t)(t + 1) * 128 * 512;
      gx0 = *(const float4*)(g0 + 0 * 32 * 512);
      gx1 = *(const float4*)(g0 + 1 * 32 * 512);
      gx2 = *(const float4*)(g0 + 2 * 32 * 512);
      gx3 = *(const float4*)(g0 + 3 * 32 * 512);
    }
  }
}

// ---------------- FC GEMM: out[b][t][v] = hs @ fc_W^T + fc_b ----------------
// M=2048 (rows t*32+b), N=10000, K=512. 128x128 block tile, wave = 64x64.

__global__ __launch_bounds__(256) void gemm_fc_kernel(const short* __restrict__ A,
                                                      const short* __restrict__ W,
                                                      const float* __restrict__ bias,
                                                      float* __restrict__ out) {
  const int lane = threadIdx.x & 63;
  const int wv   = threadIdx.x >> 6;
  const int m0 = blockIdx.y * 128 + (wv >> 1) * 64;
  const int n0 = blockIdx.x * 128 + (wv & 1) * 64;
  const int lr = lane & 15;
  const int ko = (lane >> 4) << 3;
  f32x4 acc[4][4] = {};
  const short* Ap = A + (m0 + lr) * 512 + ko;
  const short* Wp[4];
  bool vn[4];
#pragma unroll
  for (int ni = 0; ni < 4; ++ni) {
    int nr = n0 + ni * 16 + lr;
    vn[ni] = nr < V_;
    Wp[ni] = W + (size_t)(vn[ni] ? nr : 0) * 512 + ko;
  }
  const bf16x8 zb = {};
#pragma unroll 2
  for (int k = 0; k < 512; k += 32) {
    bf16x8 af[4], bf[4];
#pragma unroll
    for (int mi = 0; mi < 4; ++mi) af[mi] = *(const bf16x8*)(Ap + mi * 16 * 512 + k);
#pragma unroll
    for (int ni = 0; ni < 4; ++ni) bf[ni] = vn[ni] ? *(const bf16x8*)(Wp[ni] + k) : zb;
#pragma unroll
    for (int mi = 0; mi < 4; ++mi)
#pragma unroll
      for (int ni = 0; ni < 4; ++ni)
        acc[mi][ni] = mfma16(af[mi], bf[ni], acc[mi][ni]);
  }
  const int cr = (lane >> 4) * 4, cc = lane & 15;
#pragma unroll
  for (int mi = 0; mi < 4; ++mi)
#pragma unroll
    for (int ni = 0; ni < 4; ++ni)
#pragma unroll
      for (int j = 0; j < 4; ++j) {
        int row = m0 + mi * 16 + cr + j;
        int col = n0 + ni * 16 + cc;
        if (col < V_) {
          // row = t*32 + b  ->  out[b][t][col]
          out[(row & 31) * (T_ * V_) + (row >> 5) * V_ + col] = acc[mi][ni][j] + bias[col];
        }
      }
}

// ---------------- launch ----------------

extern "C" void kernel_launch(void* const* d_in, const int* in_sizes, int n_in,
                              void* d_out, int out_size, void* d_ws, size_t ws_size,
                              hipStream_t stream) {
  const float* features = (const float*)d_in[0];
  const int*   captions = (const int*)d_in[1];
  const float* embed    = (const float*)d_in[3];
  const float* W_ih     = (const float*)d_in[4];
  const float* W_hh     = (const float*)d_in[5];
  const float* b_ih     = (const float*)d_in[6];
  const float* b_hh     = (const float*)d_in[7];
  const float* fc_W     = (const float*)d_in[8];
  const float* fc_b     = (const float*)d_in[9];
  float* out = (float*)d_out;

  char* ws = (char*)d_ws;
  size_t off = 0;
  auto alloc = [&](size_t bytes) -> void* {
    off = (off + 255) & ~(size_t)255;
    void* p = ws + off;
    off += bytes;
    return p;
  };
  short*    wih_bf = (short*)   alloc((size_t)G4 * E_ * 2);
  short*    whh_bf = (short*)   alloc((size_t)G4 * H_ * 2);
  short*    fcw_bf = (short*)   alloc((size_t)V_ * H_ * 2);
  float*    bsum   = (float*)   alloc((size_t)G4 * 4);
  float*    Gx     = (float*)   alloc((size_t)T_ * B_ * G4 * 4);
  short*    xs     = (short*)   alloc((size_t)T_ * B_ * E_ * 2);
  short*    hs     = (short*)   alloc((size_t)T_ * B_ * H_ * 2);

  prep_kernel<<<2048, 256, 0, stream>>>(W_ih, W_hh, fc_W, b_ih, b_hh,
                                        features, captions, embed,
                                        wih_bf, whh_bf, fcw_bf, bsum, xs,
                                        (unsigned long long*)hs);
  gemm_gx_kernel<<<dim3(32, 32), 256, 0, stream>>>(xs, wih_bf, bsum, Gx);
  lstm_kernel<<<64, 64, 0, stream>>>(whh_bf, Gx, hs);
  gemm_fc_kernel<<<dim3(79, 16), 256, 0, stream>>>(hs, fcw_bf, fc_b, out);
}

// Round 11
// 381.233 us; speedup vs baseline: 1.0545x; 1.0545x over previous
//
#include <hip/hip_runtime.h>
#include <hip/hip_bf16.h>

// Problem constants
#define B_ 32
#define T_ 64
#define E_ 512
#define H_ 512
#define V_ 10000
#define G4 2048   // 4*H

#define NLSTM 64          // recurrence blocks (2 batch-groups x 32 col-slots)
#define NFC   160         // persistent FC-consumer blocks
#define NT_TILES 79       // ceil(V_/128) n-tiles per t

using bf16x8 = __attribute__((ext_vector_type(8))) short;  // 8 bf16 in 4 VGPRs
using f32x4  = __attribute__((ext_vector_type(4))) float;

__device__ inline f32x4 mfma16(bf16x8 a, bf16x8 b, f32x4 c) {
  return __builtin_amdgcn_mfma_f32_16x16x32_bf16(a, b, c, 0, 0, 0);
}

// fp32 -> bf16 round-to-nearest-even, stored as short
__device__ inline short f2bf(float x) {
  unsigned u = __builtin_bit_cast(unsigned, x);
  u = (u + 0x7fffu + ((u >> 16) & 1u)) >> 16;
  return (short)u;
}

// fast transcendental pointwise (bf16-output accuracy is the bar)
__device__ inline float fsigm(float x) {
  return __builtin_amdgcn_rcpf(1.f + __builtin_amdgcn_exp2f(-1.442695040888963f * x));
}
__device__ inline float ftanh(float x) {
  return 1.f - 2.f * __builtin_amdgcn_rcpf(1.f + __builtin_amdgcn_exp2f(2.885390081777927f * x));
}

// Swizzled 16B LDS read: row stride 1024B, byte ^= (row&7)<<4 kills the
// 16-way bank conflict of the row-major [*][512] bf16 layout (guide G4).
__device__ inline bf16x8 lds_ld16B(const short* base, int row, int col) {
  int byte = (row << 10) + (col << 1);
  byte ^= (row & 7) << 4;
  return *(const bf16x8*)((const char*)base + byte);
}

// ---------------- fused prep kernel ----------------
// One grid-stride kernel: cast W_ih, W_hh, fc_W to bf16; bsum; build xs.

#define N1 (G4 * E_)                 // W_ih
#define N2 (N1 + G4 * H_)            // W_hh
#define N3 (N2 + V_ * H_)            // fc_W
#define N4 (N3 + G4)                 // bsum
#define N5 (N4 + T_ * B_ * E_)       // xs

__global__ void prep_kernel(const float* __restrict__ W_ih, const float* __restrict__ W_hh,
                            const float* __restrict__ fc_W, const float* __restrict__ b_ih,
                            const float* __restrict__ b_hh, const float* __restrict__ features,
                            const int* __restrict__ captions, const float* __restrict__ embed,
                            short* __restrict__ wih_bf, short* __restrict__ whh_bf,
                            short* __restrict__ fcw_bf, float* __restrict__ bsum,
                            short* __restrict__ xs) {
  int i = blockIdx.x * blockDim.x + threadIdx.x;
  int stride = gridDim.x * blockDim.x;
  for (; i < N5; i += stride) {
    if (i < N1) {
      wih_bf[i] = f2bf(W_ih[i]);
    } else if (i < N2) {
      int j = i - N1;
      whh_bf[j] = f2bf(W_hh[j]);
    } else if (i < N3) {
      int j = i - N2;
      fcw_bf[j] = f2bf(fc_W[j]);
    } else if (i < N4) {
      int j = i - N3;
      bsum[j] = b_ih[j] + b_hh[j];
    } else {
      int j = i - N4;                 // [t][b][e]
      int t = j / (B_ * E_);
      int r = j - t * (B_ * E_);
      int b = r >> 9;
      int e = r & 511;
      float v;
      if (t == 0) v = features[b * E_ + e];
      else        v = embed[captions[b * T_ + (t - 1)] * E_ + e];
      xs[j] = f2bf(v);
    }
  }
}

// ---------------- Gx GEMM ----------------
// Computes xs @ W_ih^T + (b_ih+b_hh), M=2048 (t*32+b), N=2048 (g*512+hc), K=512.
// OUTPUT LAYOUT: Gxt[t][g][b][hc] = [((t*4+g)*32+b)*512 + hc].

__global__ __launch_bounds__(256) void gemm_gx_kernel(const short* __restrict__ A,
                                                      const short* __restrict__ W,
                                                      const float* __restrict__ bias,
                                                      float* __restrict__ C) {
  const int lane = threadIdx.x & 63;
  const int wv   = threadIdx.x >> 6;
  const int m0 = blockIdx.y * 64 + (wv >> 1) * 32;
  const int n0 = blockIdx.x * 64 + (wv & 1) * 32;
  const int lr = lane & 15;
  const int ko = (lane >> 4) << 3;
  f32x4 acc[2][2] = {};
  const short* Ap = A + (m0 + lr) * 512 + ko;
  const short* Wp = W + (n0 + lr) * 512 + ko;
#pragma unroll
  for (int k = 0; k < 512; k += 32) {
    bf16x8 a0 = *(const bf16x8*)(Ap + k);
    bf16x8 a1 = *(const bf16x8*)(Ap + 16 * 512 + k);
    bf16x8 b0 = *(const bf16x8*)(Wp + k);
    bf16x8 b1 = *(const bf16x8*)(Wp + 16 * 512 + k);
    acc[0][0] = mfma16(a0, b0, acc[0][0]);
    acc[0][1] = mfma16(a0, b1, acc[0][1]);
    acc[1][0] = mfma16(a1, b0, acc[1][0]);
    acc[1][1] = mfma16(a1, b1, acc[1][1]);
  }
  const int cr = (lane >> 4) * 4, cc = lane & 15;
#pragma unroll
  for (int mi = 0; mi < 2; ++mi)
#pragma unroll
    for (int ni = 0; ni < 2; ++ni)
#pragma unroll
      for (int j = 0; j < 4; ++j) {
        int row = m0 + mi * 16 + cr + j;   // t*32 + b
        int col = n0 + ni * 16 + cc;       // g*512 + hc
        int tt = row >> 5, bb = row & 31;
        int g  = col >> 9, hc = col & 511;
        C[(size_t)((tt * 4 + g) * 32 + bb) * 512 + hc] = acc[mi][ni][j] + bias[col];
      }
}

// ---------------- FUSED persistent recurrence + FC consumer ----------------
// One dispatch, 224 co-resident blocks (<= 256 CUs), role by blockIdx:
//   blocks [0,64):   R8-verified LSTM recurrence (2 groups x 32 col-slots).
//                    Flag raised for EVERY t (incl. last) so FC can consume.
//   blocks [64,224): persistent FC consumers. Walk (t, ntile) tiles in
//                    t-order; poll flags >= t+1 (atomic, s_sleep backoff),
//                    then PLAIN-load hs[t] (first cached access is strictly
//                    after the flag -> fresh; same argument as the verified
//                    R8 consumer) and MFMA vs fc_W. The 21-GFLOP FC hides
//                    under the latency-bound recurrence.

__global__ __launch_bounds__(256) void fused_kernel(const short* __restrict__ Whh,
                                                    const float* __restrict__ Gx,
                                                    short* __restrict__ hs,    // [T][B][H]
                                                    int* __restrict__ flags,   // [2][32]
                                                    const short* __restrict__ fcW,
                                                    const float* __restrict__ fcbias,
                                                    float* __restrict__ out) {
  __shared__ short Wlds[64 * 512];    // 64 KB, swizzled (lstm role only)
  const int tid = threadIdx.x;

  if (blockIdx.x < NLSTM) {
    // ================= LSTM recurrence role (R8 protocol) =================
    const int blk  = blockIdx.x;
    const int bg   = blk >> 5;          // batch group 0/1
    const int slot = blk & 31;          // h-column slot
    const int hc0  = slot * 16;
    int* const gflags = flags + bg * 32;

    // stage W_hh slice (swizzled) with all 256 threads
    for (int i = tid * 8; i < 64 * 512; i += 256 * 8) {
      int gc = i >> 9;
      int k  = i & 511;
      int g  = gc >> 4, c = gc & 15;
      bf16x8 v = *(const bf16x8*)&Whh[(g * 512 + hc0 + c) * 512 + k];
      int byte = (i * 2) ^ ((gc & 7) << 4);
      *(bf16x8*)((char*)Wlds + byte) = v;
    }
    __syncthreads();
    if (tid >= 64) return;   // waves 1-3 done (no further barriers below)

    const int lane = tid;
    const int lr  = lane & 15;
    const int ko  = (lane >> 4) << 3;   // k-offset within 32-chunk
    const int cr  = (lane >> 4) << 2;   // hcol-rel base (0,4,8,12)
    const int cc  = lane & 15;
    const int bat = bg * 16 + cc;       // global batch of this lane's cells
    const int hrow = bg * 16 + lr;      // h row this lane loads for B-frag

    const float* gbase = Gx + (size_t)bat * 512 + hc0 + cr;
    float4 gx0 = *(const float4*)(gbase + 0 * 32 * 512);
    float4 gx1 = *(const float4*)(gbase + 1 * 32 * 512);
    float4 gx2 = *(const float4*)(gbase + 2 * 32 * 512);
    float4 gx3 = *(const float4*)(gbase + 3 * 32 * 512);

    float cst[4] = {0.f, 0.f, 0.f, 0.f};

    for (int t = 0; t < T_; ++t) {
      f32x4 a0 = {}, a1 = {}, a2 = {}, a3 = {};
      if (t > 0) {
        const int* fp = gflags + (lane & 31);
        for (;;) {
          int fl = __hip_atomic_load(fp, __ATOMIC_RELAXED, __HIP_MEMORY_SCOPE_AGENT);
          if (__all(fl >= t)) break;
        }
        asm volatile("" ::: "memory");
        const short* Ap = hs + (size_t)(t - 1) * (B_ * H_) + hrow * 512 + ko;
#pragma unroll
        for (int kk = 0; kk < 512; kk += 32) {
          bf16x8 hb = *(const bf16x8*)(Ap + kk);
          bf16x8 w0 = lds_ld16B(Wlds,      lr, kk + ko);
          bf16x8 w1 = lds_ld16B(Wlds, 16 + lr, kk + ko);
          bf16x8 w2 = lds_ld16B(Wlds, 32 + lr, kk + ko);
          bf16x8 w3 = lds_ld16B(Wlds, 48 + lr, kk + ko);
          a0 = mfma16(w0, hb, a0);
          a1 = mfma16(w1, hb, a1);
          a2 = mfma16(w2, hb, a2);
          a3 = mfma16(w3, hb, a3);
        }
      }
      unsigned long long hpack = 0;
#pragma unroll
      for (int j = 0; j < 4; ++j) {
        float iv = fsigm(a0[j] + ((const float*)&gx0)[j]);
        float fv = fsigm(a1[j] + ((const float*)&gx1)[j]);
        float gv = ftanh(a2[j] + ((const float*)&gx2)[j]);
        float ov = fsigm(a3[j] + ((const float*)&gx3)[j]);
        float cv = fv * cst[j] + iv * gv;
        cst[j] = cv;
        float hv = ov * ftanh(cv);
        hpack |= (unsigned long long)(unsigned short)f2bf(hv) << (16 * j);
      }
      __hip_atomic_store(
          (unsigned long long*)(hs + (size_t)t * (B_ * H_) + bat * 512 + hc0 + cr),
          hpack, __ATOMIC_RELAXED, __HIP_MEMORY_SCOPE_AGENT);
      // drain own store, then raise this block's flag — EVERY t (FC needs t=63)
      asm volatile("s_waitcnt vmcnt(0)" ::: "memory");
      if (lane == 0)
        __hip_atomic_store(gflags + slot, t + 1, __ATOMIC_RELAXED,
                           __HIP_MEMORY_SCOPE_AGENT);
      if (t < T_ - 1) {
        const float* g0 = gbase + (size_t)(t + 1) * 128 * 512;
        gx0 = *(const float4*)(g0 + 0 * 32 * 512);
        gx1 = *(const float4*)(g0 + 1 * 32 * 512);
        gx2 = *(const float4*)(g0 + 2 * 32 * 512);
        gx3 = *(const float4*)(g0 + 3 * 32 * 512);
      }
    }
  } else {
    // ================= FC consumer role =================
    const int fblk = blockIdx.x - NLSTM;
    const int lane = tid & 63;
    const int wv   = tid >> 6;
    const int lr   = lane & 15;
    const int ko   = (lane >> 4) << 3;
    const int cr   = (lane >> 4) * 4, cc = lane & 15;
    const bf16x8 zb = {};
    int tcur = -1;   // last t whose flags are confirmed

    for (int tau = fblk; tau < T_ * NT_TILES; tau += NFC) {
      const int t  = tau / NT_TILES;
      const int nt = tau - t * NT_TILES;
      if (t > tcur) {
        // poll all 64 producer flags >= t+1 (hs[t] complete), with backoff
        const int* fp = flags + lane;
        for (;;) {
          int fl = __hip_atomic_load(fp, __ATOMIC_RELAXED, __HIP_MEMORY_SCOPE_AGENT);
          if (__all(fl >= t + 1)) break;
          __builtin_amdgcn_s_sleep(8);
        }
        asm volatile("" ::: "memory");
        tcur = t;
      }
      // 32x128 tile: wave wv covers cols [nt*128+wv*32, +32), all 32 rows
      const short* A  = hs + (size_t)t * (B_ * H_);
      const int n0 = nt * 128 + wv * 32;
      const int nr0 = n0 + lr, nr1 = n0 + 16 + lr;
      const bool v0 = nr0 < V_, v1 = nr1 < V_;
      f32x4 acc[2][2] = {};
      const short* Ap  = A + lr * 512 + ko;
      const short* Wp0 = fcW + (size_t)(v0 ? nr0 : 0) * 512 + ko;
      const short* Wp1 = fcW + (size_t)(v1 ? nr1 : 0) * 512 + ko;
#pragma unroll
      for (int k = 0; k < 512; k += 32) {
        bf16x8 a0 = *(const bf16x8*)(Ap + k);
        bf16x8 a1 = *(const bf16x8*)(Ap + 16 * 512 + k);
        bf16x8 b0 = v0 ? *(const bf16x8*)(Wp0 + k) : zb;
        bf16x8 b1 = v1 ? *(const bf16x8*)(Wp1 + k) : zb;
        acc[0][0] = mfma16(a0, b0, acc[0][0]);
        acc[0][1] = mfma16(a0, b1, acc[0][1]);
        acc[1][0] = mfma16(a1, b0, acc[1][0]);
        acc[1][1] = mfma16(a1, b1, acc[1][1]);
      }
#pragma unroll
      for (int mi = 0; mi < 2; ++mi)
#pragma unroll
        for (int ni = 0; ni < 2; ++ni)
#pragma unroll
          for (int j = 0; j < 4; ++j) {
            int bat = mi * 16 + cr + j;          // row = batch
            int col = n0 + ni * 16 + cc;
            if (col < V_)
              out[(size_t)bat * (T_ * V_) + t * V_ + col] = acc[mi][ni][j] + fcbias[col];
          }
    }
  }
}

// ---------------- launch ----------------

extern "C" void kernel_launch(void* const* d_in, const int* in_sizes, int n_in,
                              void* d_out, int out_size, void* d_ws, size_t ws_size,
                              hipStream_t stream) {
  const float* features = (const float*)d_in[0];
  const int*   captions = (const int*)d_in[1];
  const float* embed    = (const float*)d_in[3];
  const float* W_ih     = (const float*)d_in[4];
  const float* W_hh     = (const float*)d_in[5];
  const float* b_ih     = (const float*)d_in[6];
  const float* b_hh     = (const float*)d_in[7];
  const float* fc_W     = (const float*)d_in[8];
  const float* fc_b     = (const float*)d_in[9];
  float* out = (float*)d_out;

  char* ws = (char*)d_ws;
  size_t off = 0;
  auto alloc = [&](size_t bytes) -> void* {
    off = (off + 255) & ~(size_t)255;
    void* p = ws + off;
    off += bytes;
    return p;
  };
  int*      flags  = (int*)     alloc(4096);
  short*    wih_bf = (short*)   alloc((size_t)G4 * E_ * 2);
  short*    whh_bf = (short*)   alloc((size_t)G4 * H_ * 2);
  short*    fcw_bf = (short*)   alloc((size_t)V_ * H_ * 2);
  float*    bsum   = (float*)   alloc((size_t)G4 * 4);
  float*    Gx     = (float*)   alloc((size_t)T_ * B_ * G4 * 4);
  short*    xs     = (short*)   alloc((size_t)T_ * B_ * E_ * 2);
  short*    hs     = (short*)   alloc((size_t)T_ * B_ * H_ * 2);

  (void)hipMemsetAsync(flags, 0, 4096, stream);
  prep_kernel<<<2048, 256, 0, stream>>>(W_ih, W_hh, fc_W, b_ih, b_hh,
                                        features, captions, embed,
                                        wih_bf, whh_bf, fcw_bf, bsum, xs);
  gemm_gx_kernel<<<dim3(32, 32), 256, 0, stream>>>(xs, wih_bf, bsum, Gx);
  fused_kernel<<<NLSTM + NFC, 256, 0, stream>>>(whh_bf, Gx, hs, flags,
                                                fcw_bf, fc_b, out);
}

// Round 12
// 343.030 us; speedup vs baseline: 1.1719x; 1.1114x over previous
//
#include <hip/hip_runtime.h>
#include <hip/hip_bf16.h>

// Problem constants
#define B_ 32
#define T_ 64
#define E_ 512
#define H_ 512
#define V_ 10000
#define G4 2048   // 4*H

#define NLSTM 64          // recurrence blocks (2 batch-groups x 32 col-slots)
#define NFC   157         // FC consumer blocks: one 64-col n-tile each
#define NTOT  (NLSTM + NFC)

using bf16x8 = __attribute__((ext_vector_type(8))) short;  // 8 bf16 in 4 VGPRs
using f32x4  = __attribute__((ext_vector_type(4))) float;

__device__ inline f32x4 mfma16(bf16x8 a, bf16x8 b, f32x4 c) {
  return __builtin_amdgcn_mfma_f32_16x16x32_bf16(a, b, c, 0, 0, 0);
}

// fp32 -> bf16 round-to-nearest-even, stored as short
__device__ inline short f2bf(float x) {
  unsigned u = __builtin_bit_cast(unsigned, x);
  u = (u + 0x7fffu + ((u >> 16) & 1u)) >> 16;
  return (short)u;
}

// fast transcendental pointwise (bf16-output accuracy is the bar)
__device__ inline float fsigm(float x) {
  return __builtin_amdgcn_rcpf(1.f + __builtin_amdgcn_exp2f(-1.442695040888963f * x));
}
__device__ inline float ftanh(float x) {
  return 1.f - 2.f * __builtin_amdgcn_rcpf(1.f + __builtin_amdgcn_exp2f(2.885390081777927f * x));
}

// Swizzled 16B LDS read: row stride 1024B, byte ^= (row&7)<<4 kills the
// 16-way bank conflict of the row-major [*][512] bf16 layout (guide G4).
__device__ inline bf16x8 lds_ld16B(const short* base, int row, int col) {
  int byte = (row << 10) + (col << 1);
  byte ^= (row & 7) << 4;
  return *(const bf16x8*)((const char*)base + byte);
}

// ---------------- fused prep kernel ----------------
// One grid-stride kernel: cast W_ih, W_hh, fc_W to bf16; bsum; build xs.

#define N1 (G4 * E_)                 // W_ih
#define N2 (N1 + G4 * H_)            // W_hh
#define N3 (N2 + V_ * H_)            // fc_W
#define N4 (N3 + G4)                 // bsum
#define N5 (N4 + T_ * B_ * E_)       // xs

__global__ void prep_kernel(const float* __restrict__ W_ih, const float* __restrict__ W_hh,
                            const float* __restrict__ fc_W, const float* __restrict__ b_ih,
                            const float* __restrict__ b_hh, const float* __restrict__ features,
                            const int* __restrict__ captions, const float* __restrict__ embed,
                            short* __restrict__ wih_bf, short* __restrict__ whh_bf,
                            short* __restrict__ fcw_bf, float* __restrict__ bsum,
                            short* __restrict__ xs) {
  int i = blockIdx.x * blockDim.x + threadIdx.x;
  int stride = gridDim.x * blockDim.x;
  for (; i < N5; i += stride) {
    if (i < N1) {
      wih_bf[i] = f2bf(W_ih[i]);
    } else if (i < N2) {
      int j = i - N1;
      whh_bf[j] = f2bf(W_hh[j]);
    } else if (i < N3) {
      int j = i - N2;
      fcw_bf[j] = f2bf(fc_W[j]);
    } else if (i < N4) {
      int j = i - N3;
      bsum[j] = b_ih[j] + b_hh[j];
    } else {
      int j = i - N4;                 // [t][b][e]
      int t = j / (B_ * E_);
      int r = j - t * (B_ * E_);
      int b = r >> 9;
      int e = r & 511;
      float v;
      if (t == 0) v = features[b * E_ + e];
      else        v = embed[captions[b * T_ + (t - 1)] * E_ + e];
      xs[j] = f2bf(v);
    }
  }
}

// ---------------- Gx GEMM ----------------
// Computes xs @ W_ih^T + (b_ih+b_hh), M=2048 (t*32+b), N=2048 (g*512+hc), K=512.
// OUTPUT LAYOUT: Gxt[t][g][b][hc] = [((t*4+g)*32+b)*512 + hc].

__global__ __launch_bounds__(256) void gemm_gx_kernel(const short* __restrict__ A,
                                                      const short* __restrict__ W,
                                                      const float* __restrict__ bias,
                                                      float* __restrict__ C) {
  const int lane = threadIdx.x & 63;
  const int wv   = threadIdx.x >> 6;
  const int m0 = blockIdx.y * 64 + (wv >> 1) * 32;
  const int n0 = blockIdx.x * 64 + (wv & 1) * 32;
  const int lr = lane & 15;
  const int ko = (lane >> 4) << 3;
  f32x4 acc[2][2] = {};
  const short* Ap = A + (m0 + lr) * 512 + ko;
  const short* Wp = W + (n0 + lr) * 512 + ko;
#pragma unroll
  for (int k = 0; k < 512; k += 32) {
    bf16x8 a0 = *(const bf16x8*)(Ap + k);
    bf16x8 a1 = *(const bf16x8*)(Ap + 16 * 512 + k);
    bf16x8 b0 = *(const bf16x8*)(Wp + k);
    bf16x8 b1 = *(const bf16x8*)(Wp + 16 * 512 + k);
    acc[0][0] = mfma16(a0, b0, acc[0][0]);
    acc[0][1] = mfma16(a0, b1, acc[0][1]);
    acc[1][0] = mfma16(a1, b0, acc[1][0]);
    acc[1][1] = mfma16(a1, b1, acc[1][1]);
  }
  const int cr = (lane >> 4) * 4, cc = lane & 15;
#pragma unroll
  for (int mi = 0; mi < 2; ++mi)
#pragma unroll
    for (int ni = 0; ni < 2; ++ni)
#pragma unroll
      for (int j = 0; j < 4; ++j) {
        int row = m0 + mi * 16 + cr + j;   // t*32 + b
        int col = n0 + ni * 16 + cc;       // g*512 + hc
        int tt = row >> 5, bb = row & 31;
        int g  = col >> 9, hc = col & 511;
        C[(size_t)((tt * 4 + g) * 32 + bb) * 512 + hc] = acc[mi][ni][j] + bias[col];
      }
}

// ---------------- FUSED persistent recurrence + FC consumer ----------------
// 221 co-resident blocks, role by blockIdx:
//   [0,64):    R8-verified LSTM recurrence; flag raised every t.
//   [64,221):  FC consumers, N-MAJOR: block owns ONE 64-col n-tile; its
//              fc_W slice (64x512 bf16 = 64KB) staged in LDS ONCE; loop
//              t=0..63 {poll flags >= t+1, plain-load hs[t] (32KB, L2/L3
//              resident), 32 MFMA/wave, write 32x64 out tile}. fc_W is
//              fetched once total (10MB) instead of once per t (350MB, the
//              R11 regression).

__global__ __launch_bounds__(256) void fused_kernel(const short* __restrict__ Whh,
                                                    const float* __restrict__ Gx,
                                                    short* __restrict__ hs,    // [T][B][H]
                                                    int* __restrict__ flags,   // [2][32]
                                                    const short* __restrict__ fcW,
                                                    const float* __restrict__ fcbias,
                                                    float* __restrict__ out) {
  __shared__ short Wlds[64 * 512];    // 64 KB swizzled (both roles)
  const int tid = threadIdx.x;

  if (blockIdx.x < NLSTM) {
    // ================= LSTM recurrence role (R8 protocol) =================
    const int blk  = blockIdx.x;
    const int bg   = blk >> 5;          // batch group 0/1
    const int slot = blk & 31;          // h-column slot
    const int hc0  = slot * 16;
    int* const gflags = flags + bg * 32;

    // stage W_hh slice (swizzled) with all 256 threads
    for (int i = tid * 8; i < 64 * 512; i += 256 * 8) {
      int gc = i >> 9;
      int k  = i & 511;
      int g  = gc >> 4, c = gc & 15;
      bf16x8 v = *(const bf16x8*)&Whh[(g * 512 + hc0 + c) * 512 + k];
      int byte = (i * 2) ^ ((gc & 7) << 4);
      *(bf16x8*)((char*)Wlds + byte) = v;
    }
    __syncthreads();
    if (tid >= 64) return;   // waves 1-3 done (no further barriers below)

    const int lane = tid;
    const int lr  = lane & 15;
    const int ko  = (lane >> 4) << 3;   // k-offset within 32-chunk
    const int cr  = (lane >> 4) << 2;   // hcol-rel base (0,4,8,12)
    const int cc  = lane & 15;
    const int bat = bg * 16 + cc;       // global batch of this lane's cells
    const int hrow = bg * 16 + lr;      // h row this lane loads for B-frag

    const float* gbase = Gx + (size_t)bat * 512 + hc0 + cr;
    float4 gx0 = *(const float4*)(gbase + 0 * 32 * 512);
    float4 gx1 = *(const float4*)(gbase + 1 * 32 * 512);
    float4 gx2 = *(const float4*)(gbase + 2 * 32 * 512);
    float4 gx3 = *(const float4*)(gbase + 3 * 32 * 512);

    float cst[4] = {0.f, 0.f, 0.f, 0.f};

    for (int t = 0; t < T_; ++t) {
      f32x4 a0 = {}, a1 = {}, a2 = {}, a3 = {};
      if (t > 0) {
        const int* fp = gflags + (lane & 31);
        for (;;) {
          int fl = __hip_atomic_load(fp, __ATOMIC_RELAXED, __HIP_MEMORY_SCOPE_AGENT);
          if (__all(fl >= t)) break;
        }
        asm volatile("" ::: "memory");
        const short* Ap = hs + (size_t)(t - 1) * (B_ * H_) + hrow * 512 + ko;
#pragma unroll
        for (int kk = 0; kk < 512; kk += 32) {
          bf16x8 hb = *(const bf16x8*)(Ap + kk);
          bf16x8 w0 = lds_ld16B(Wlds,      lr, kk + ko);
          bf16x8 w1 = lds_ld16B(Wlds, 16 + lr, kk + ko);
          bf16x8 w2 = lds_ld16B(Wlds, 32 + lr, kk + ko);
          bf16x8 w3 = lds_ld16B(Wlds, 48 + lr, kk + ko);
          a0 = mfma16(w0, hb, a0);
          a1 = mfma16(w1, hb, a1);
          a2 = mfma16(w2, hb, a2);
          a3 = mfma16(w3, hb, a3);
        }
      }
      unsigned long long hpack = 0;
#pragma unroll
      for (int j = 0; j < 4; ++j) {
        float iv = fsigm(a0[j] + ((const float*)&gx0)[j]);
        float fv = fsigm(a1[j] + ((const float*)&gx1)[j]);
        float gv = ftanh(a2[j] + ((const float*)&gx2)[j]);
        float ov = fsigm(a3[j] + ((const float*)&gx3)[j]);
        float cv = fv * cst[j] + iv * gv;
        cst[j] = cv;
        float hv = ov * ftanh(cv);
        hpack |= (unsigned long long)(unsigned short)f2bf(hv) << (16 * j);
      }
      __hip_atomic_store(
          (unsigned long long*)(hs + (size_t)t * (B_ * H_) + bat * 512 + hc0 + cr),
          hpack, __ATOMIC_RELAXED, __HIP_MEMORY_SCOPE_AGENT);
      // drain own store, then raise this block's flag — EVERY t (FC needs t=63)
      asm volatile("s_waitcnt vmcnt(0)" ::: "memory");
      if (lane == 0)
        __hip_atomic_store(gflags + slot, t + 1, __ATOMIC_RELAXED,
                           __HIP_MEMORY_SCOPE_AGENT);
      if (t < T_ - 1) {
        const float* g0 = gbase + (size_t)(t + 1) * 128 * 512;
        gx0 = *(const float4*)(g0 + 0 * 32 * 512);
        gx1 = *(const float4*)(g0 + 1 * 32 * 512);
        gx2 = *(const float4*)(g0 + 2 * 32 * 512);
        gx3 = *(const float4*)(g0 + 3 * 32 * 512);
      }
    }
  } else {
    // ================= FC consumer role (n-major, fc_W in LDS) =============
    const int fblk = blockIdx.x - NLSTM;   // 0..156
    const int n0   = fblk * 64;            // this block's 64 output cols
    const int lane = tid & 63;
    const int wv   = tid >> 6;
    const int lr   = lane & 15;
    const int ko   = (lane >> 4) << 3;
    const int cr   = (lane >> 4) * 4, cc = lane & 15;

    // stage fc_W rows n0..n0+63 into swizzled LDS once (clamp OOB rows)
    for (int i = tid * 8; i < 64 * 512; i += 256 * 8) {
      int gc = i >> 9;
      int k  = i & 511;
      int nr = n0 + gc; if (nr >= V_) nr = V_ - 1;
      bf16x8 v = *(const bf16x8*)&fcW[(size_t)nr * 512 + k];
      int byte = (i * 2) ^ ((gc & 7) << 4);
      *(bf16x8*)((char*)Wlds + byte) = v;
    }
    __syncthreads();   // Wlds read-only afterwards; waves drift freely

    const int colw = n0 + wv * 16 + cc;        // this lane's output col
    const bool wok = colw < V_;
    const float bias = wok ? fcbias[colw] : 0.f;

    for (int t = 0; t < T_; ++t) {
      // poll all 64 producer flags >= t+1 (hs[t] complete), with backoff
      const int* fp = flags + lane;
      for (;;) {
        int fl = __hip_atomic_load(fp, __ATOMIC_RELAXED, __HIP_MEMORY_SCOPE_AGENT);
        if (__all(fl >= t + 1)) break;
        __builtin_amdgcn_s_sleep(8);
      }
      asm volatile("" ::: "memory");
      // 32x16 tile per wave: A = hs[t] rows (batch), B = Wlds rows wv*16+lr
      const short* Ap = hs + (size_t)t * (B_ * H_) + lr * 512 + ko;
      f32x4 acc0 = {}, acc1 = {};
#pragma unroll
      for (int k = 0; k < 512; k += 32) {
        bf16x8 a0 = *(const bf16x8*)(Ap + k);
        bf16x8 a1 = *(const bf16x8*)(Ap + 16 * 512 + k);
        bf16x8 b  = lds_ld16B(Wlds, wv * 16 + lr, k + ko);
        acc0 = mfma16(a0, b, acc0);
        acc1 = mfma16(a1, b, acc1);
      }
      if (wok) {
#pragma unroll
        for (int j = 0; j < 4; ++j) {
          out[(size_t)(cr + j) * (T_ * V_) + t * V_ + colw]      = acc0[j] + bias;
          out[(size_t)(16 + cr + j) * (T_ * V_) + t * V_ + colw] = acc1[j] + bias;
        }
      }
    }
  }
}

// ---------------- launch ----------------

extern "C" void kernel_launch(void* const* d_in, const int* in_sizes, int n_in,
                              void* d_out, int out_size, void* d_ws, size_t ws_size,
                              hipStream_t stream) {
  const float* features = (const float*)d_in[0];
  const int*   captions = (const int*)d_in[1];
  const float* embed    = (const float*)d_in[3];
  const float* W_ih     = (const float*)d_in[4];
  const float* W_hh     = (const float*)d_in[5];
  const float* b_ih     = (const float*)d_in[6];
  const float* b_hh     = (const float*)d_in[7];
  const float* fc_W     = (const float*)d_in[8];
  const float* fc_b     = (const float*)d_in[9];
  float* out = (float*)d_out;

  char* ws = (char*)d_ws;
  size_t off = 0;
  auto alloc = [&](size_t bytes) -> void* {
    off = (off + 255) & ~(size_t)255;
    void* p = ws + off;
    off += bytes;
    return p;
  };
  int*      flags  = (int*)     alloc(4096);
  short*    wih_bf = (short*)   alloc((size_t)G4 * E_ * 2);
  short*    whh_bf = (short*)   alloc((size_t)G4 * H_ * 2);
  short*    fcw_bf = (short*)   alloc((size_t)V_ * H_ * 2);
  float*    bsum   = (float*)   alloc((size_t)G4 * 4);
  float*    Gx     = (float*)   alloc((size_t)T_ * B_ * G4 * 4);
  short*    xs     = (short*)   alloc((size_t)T_ * B_ * E_ * 2);
  short*    hs     = (short*)   alloc((size_t)T_ * B_ * H_ * 2);

  (void)hipMemsetAsync(flags, 0, 4096, stream);
  prep_kernel<<<2048, 256, 0, stream>>>(W_ih, W_hh, fc_W, b_ih, b_hh,
                                        features, captions, embed,
                                        wih_bf, whh_bf, fcw_bf, bsum, xs);
  gemm_gx_kernel<<<dim3(32, 32), 256, 0, stream>>>(xs, wih_bf, bsum, Gx);
  fused_kernel<<<NTOT, 256, 0, stream>>>(whh_bf, Gx, hs, flags,
                                         fcw_bf, fc_b, out);
}

// Round 13
// 311.914 us; speedup vs baseline: 1.2888x; 1.0998x over previous
//
#include <hip/hip_runtime.h>
#include <hip/hip_bf16.h>

// Problem constants
#define B_ 32
#define T_ 64
#define E_ 512
#define H_ 512
#define V_ 10000
#define G4 2048   // 4*H

#define NLSTM 64          // recurrence blocks (2 batch-groups x 32 col-slots)
#define NFC   157         // FC consumer blocks: one 64-col n-tile each
#define NTOT  (NLSTM + NFC)

using bf16x8 = __attribute__((ext_vector_type(8))) short;  // 8 bf16 in 4 VGPRs
using f32x4  = __attribute__((ext_vector_type(4))) float;

__device__ inline f32x4 mfma16(bf16x8 a, bf16x8 b, f32x4 c) {
  return __builtin_amdgcn_mfma_f32_16x16x32_bf16(a, b, c, 0, 0, 0);
}

// fp32 -> bf16 round-to-nearest-even, stored as short
__device__ inline short f2bf(float x) {
  unsigned u = __builtin_bit_cast(unsigned, x);
  u = (u + 0x7fffu + ((u >> 16) & 1u)) >> 16;
  return (short)u;
}

// fast transcendental pointwise (bf16-output accuracy is the bar)
__device__ inline float fsigm(float x) {
  return __builtin_amdgcn_rcpf(1.f + __builtin_amdgcn_exp2f(-1.442695040888963f * x));
}
__device__ inline float ftanh(float x) {
  return 1.f - 2.f * __builtin_amdgcn_rcpf(1.f + __builtin_amdgcn_exp2f(2.885390081777927f * x));
}

// Swizzled 16B LDS read: row stride 1024B, byte ^= (row&7)<<4 kills the
// 16-way bank conflict of the row-major [*][512] bf16 layout (guide G4).
__device__ inline bf16x8 lds_ld16B(const short* base, int row, int col) {
  int byte = (row << 10) + (col << 1);
  byte ^= (row & 7) << 4;
  return *(const bf16x8*)((const char*)base + byte);
}

// ---------------- fused prep kernel ----------------
// One grid-stride kernel: cast W_ih, W_hh, fc_W to bf16; bsum; build xs.

#define N1 (G4 * E_)                 // W_ih
#define N2 (N1 + G4 * H_)            // W_hh
#define N3 (N2 + V_ * H_)            // fc_W
#define N4 (N3 + G4)                 // bsum
#define N5 (N4 + T_ * B_ * E_)       // xs

__global__ void prep_kernel(const float* __restrict__ W_ih, const float* __restrict__ W_hh,
                            const float* __restrict__ fc_W, const float* __restrict__ b_ih,
                            const float* __restrict__ b_hh, const float* __restrict__ features,
                            const int* __restrict__ captions, const float* __restrict__ embed,
                            short* __restrict__ wih_bf, short* __restrict__ whh_bf,
                            short* __restrict__ fcw_bf, float* __restrict__ bsum,
                            short* __restrict__ xs) {
  int i = blockIdx.x * blockDim.x + threadIdx.x;
  int stride = gridDim.x * blockDim.x;
  for (; i < N5; i += stride) {
    if (i < N1) {
      wih_bf[i] = f2bf(W_ih[i]);
    } else if (i < N2) {
      int j = i - N1;
      whh_bf[j] = f2bf(W_hh[j]);
    } else if (i < N3) {
      int j = i - N2;
      fcw_bf[j] = f2bf(fc_W[j]);
    } else if (i < N4) {
      int j = i - N3;
      bsum[j] = b_ih[j] + b_hh[j];
    } else {
      int j = i - N4;                 // [t][b][e]
      int t = j / (B_ * E_);
      int r = j - t * (B_ * E_);
      int b = r >> 9;
      int e = r & 511;
      float v;
      if (t == 0) v = features[b * E_ + e];
      else        v = embed[captions[b * T_ + (t - 1)] * E_ + e];
      xs[j] = f2bf(v);
    }
  }
}

// ---------------- Gx GEMM ----------------
// Computes xs @ W_ih^T + (b_ih+b_hh), M=2048 (t*32+b), N=2048 (g*512+hc), K=512.
// OUTPUT LAYOUT: Gxt[t][g][b][hc] = [((t*4+g)*32+b)*512 + hc].

__global__ __launch_bounds__(256) void gemm_gx_kernel(const short* __restrict__ A,
                                                      const short* __restrict__ W,
                                                      const float* __restrict__ bias,
                                                      float* __restrict__ C) {
  const int lane = threadIdx.x & 63;
  const int wv   = threadIdx.x >> 6;
  const int m0 = blockIdx.y * 64 + (wv >> 1) * 32;
  const int n0 = blockIdx.x * 64 + (wv & 1) * 32;
  const int lr = lane & 15;
  const int ko = (lane >> 4) << 3;
  f32x4 acc[2][2] = {};
  const short* Ap = A + (m0 + lr) * 512 + ko;
  const short* Wp = W + (n0 + lr) * 512 + ko;
#pragma unroll
  for (int k = 0; k < 512; k += 32) {
    bf16x8 a0 = *(const bf16x8*)(Ap + k);
    bf16x8 a1 = *(const bf16x8*)(Ap + 16 * 512 + k);
    bf16x8 b0 = *(const bf16x8*)(Wp + k);
    bf16x8 b1 = *(const bf16x8*)(Wp + 16 * 512 + k);
    acc[0][0] = mfma16(a0, b0, acc[0][0]);
    acc[0][1] = mfma16(a0, b1, acc[0][1]);
    acc[1][0] = mfma16(a1, b0, acc[1][0]);
    acc[1][1] = mfma16(a1, b1, acc[1][1]);
  }
  const int cr = (lane >> 4) * 4, cc = lane & 15;
#pragma unroll
  for (int mi = 0; mi < 2; ++mi)
#pragma unroll
    for (int ni = 0; ni < 2; ++ni)
#pragma unroll
      for (int j = 0; j < 4; ++j) {
        int row = m0 + mi * 16 + cr + j;   // t*32 + b
        int col = n0 + ni * 16 + cc;       // g*512 + hc
        int tt = row >> 5, bb = row & 31;
        int g  = col >> 9, hc = col & 511;
        C[(size_t)((tt * 4 + g) * 32 + bb) * 512 + hc] = acc[mi][ni][j] + bias[col];
      }
}

// ---------------- FUSED persistent recurrence + FC consumer ----------------
// 221 co-resident blocks, role by blockIdx:
//   [0,64):    R8-verified LSTM recurrence; flag raised every t.
//   [64,221):  FC consumers, n-major, fc_W slice in LDS. POLL DEDUP (R12
//              lesson): only wave 0 polls the 64 flags at L3 (s_sleep(32)
//              backoff ~0.85us cadence); waves 1-3 spin on an LDS counter
//              (block-local, zero fabric traffic). This cuts the R12 poll
//              storm (628 hard-spinning wave-pollers on 4 cachelines) ~16x
//              so producer flag stores stop queueing behind consumer reads.

__global__ __launch_bounds__(256) void fused_kernel(const short* __restrict__ Whh,
                                                    const float* __restrict__ Gx,
                                                    short* __restrict__ hs,    // [T][B][H]
                                                    int* __restrict__ flags,   // [2][32]
                                                    const short* __restrict__ fcW,
                                                    const float* __restrict__ fcbias,
                                                    float* __restrict__ out) {
  __shared__ short Wlds[64 * 512];    // 64 KB swizzled (both roles)
  __shared__ int tready;              // FC role: highest t known complete
  const int tid = threadIdx.x;

  if (blockIdx.x < NLSTM) {
    // ================= LSTM recurrence role (R8 protocol) =================
    const int blk  = blockIdx.x;
    const int bg   = blk >> 5;          // batch group 0/1
    const int slot = blk & 31;          // h-column slot
    const int hc0  = slot * 16;
    int* const gflags = flags + bg * 32;

    // stage W_hh slice (swizzled) with all 256 threads
    for (int i = tid * 8; i < 64 * 512; i += 256 * 8) {
      int gc = i >> 9;
      int k  = i & 511;
      int g  = gc >> 4, c = gc & 15;
      bf16x8 v = *(const bf16x8*)&Whh[(g * 512 + hc0 + c) * 512 + k];
      int byte = (i * 2) ^ ((gc & 7) << 4);
      *(bf16x8*)((char*)Wlds + byte) = v;
    }
    __syncthreads();
    if (tid >= 64) return;   // waves 1-3 done (no further barriers below)

    const int lane = tid;
    const int lr  = lane & 15;
    const int ko  = (lane >> 4) << 3;   // k-offset within 32-chunk
    const int cr  = (lane >> 4) << 2;   // hcol-rel base (0,4,8,12)
    const int cc  = lane & 15;
    const int bat = bg * 16 + cc;       // global batch of this lane's cells
    const int hrow = bg * 16 + lr;      // h row this lane loads for B-frag

    const float* gbase = Gx + (size_t)bat * 512 + hc0 + cr;
    float4 gx0 = *(const float4*)(gbase + 0 * 32 * 512);
    float4 gx1 = *(const float4*)(gbase + 1 * 32 * 512);
    float4 gx2 = *(const float4*)(gbase + 2 * 32 * 512);
    float4 gx3 = *(const float4*)(gbase + 3 * 32 * 512);

    float cst[4] = {0.f, 0.f, 0.f, 0.f};

    for (int t = 0; t < T_; ++t) {
      f32x4 a0 = {}, a1 = {}, a2 = {}, a3 = {};
      if (t > 0) {
        const int* fp = gflags + (lane & 31);
        for (;;) {
          int fl = __hip_atomic_load(fp, __ATOMIC_RELAXED, __HIP_MEMORY_SCOPE_AGENT);
          if (__all(fl >= t)) break;
        }
        asm volatile("" ::: "memory");
        const short* Ap = hs + (size_t)(t - 1) * (B_ * H_) + hrow * 512 + ko;
#pragma unroll
        for (int kk = 0; kk < 512; kk += 32) {
          bf16x8 hb = *(const bf16x8*)(Ap + kk);
          bf16x8 w0 = lds_ld16B(Wlds,      lr, kk + ko);
          bf16x8 w1 = lds_ld16B(Wlds, 16 + lr, kk + ko);
          bf16x8 w2 = lds_ld16B(Wlds, 32 + lr, kk + ko);
          bf16x8 w3 = lds_ld16B(Wlds, 48 + lr, kk + ko);
          a0 = mfma16(w0, hb, a0);
          a1 = mfma16(w1, hb, a1);
          a2 = mfma16(w2, hb, a2);
          a3 = mfma16(w3, hb, a3);
        }
      }
      unsigned long long hpack = 0;
#pragma unroll
      for (int j = 0; j < 4; ++j) {
        float iv = fsigm(a0[j] + ((const float*)&gx0)[j]);
        float fv = fsigm(a1[j] + ((const float*)&gx1)[j]);
        float gv = ftanh(a2[j] + ((const float*)&gx2)[j]);
        float ov = fsigm(a3[j] + ((const float*)&gx3)[j]);
        float cv = fv * cst[j] + iv * gv;
        cst[j] = cv;
        float hv = ov * ftanh(cv);
        hpack |= (unsigned long long)(unsigned short)f2bf(hv) << (16 * j);
      }
      __hip_atomic_store(
          (unsigned long long*)(hs + (size_t)t * (B_ * H_) + bat * 512 + hc0 + cr),
          hpack, __ATOMIC_RELAXED, __HIP_MEMORY_SCOPE_AGENT);
      // drain own store, then raise this block's flag — EVERY t (FC needs t=63)
      asm volatile("s_waitcnt vmcnt(0)" ::: "memory");
      if (lane == 0)
        __hip_atomic_store(gflags + slot, t + 1, __ATOMIC_RELAXED,
                           __HIP_MEMORY_SCOPE_AGENT);
      if (t < T_ - 1) {
        const float* g0 = gbase + (size_t)(t + 1) * 128 * 512;
        gx0 = *(const float4*)(g0 + 0 * 32 * 512);
        gx1 = *(const float4*)(g0 + 1 * 32 * 512);
        gx2 = *(const float4*)(g0 + 2 * 32 * 512);
        gx3 = *(const float4*)(g0 + 3 * 32 * 512);
      }
    }
  } else {
    // ================= FC consumer role (n-major, fc_W in LDS) =============
    const int fblk = blockIdx.x - NLSTM;   // 0..156
    const int n0   = fblk * 64;            // this block's 64 output cols
    const int lane = tid & 63;
    const int wv   = tid >> 6;
    const int lr   = lane & 15;
    const int ko   = (lane >> 4) << 3;

    if (tid == 0)
      __hip_atomic_store(&tready, 0, __ATOMIC_RELAXED, __HIP_MEMORY_SCOPE_WORKGROUP);

    // stage fc_W rows n0..n0+63 into swizzled LDS once (clamp OOB rows)
    for (int i = tid * 8; i < 64 * 512; i += 256 * 8) {
      int gc = i >> 9;
      int k  = i & 511;
      int nr = n0 + gc; if (nr >= V_) nr = V_ - 1;
      bf16x8 v = *(const bf16x8*)&fcW[(size_t)nr * 512 + k];
      int byte = (i * 2) ^ ((gc & 7) << 4);
      *(bf16x8*)((char*)Wlds + byte) = v;
    }
    __syncthreads();   // covers tready init + Wlds staging

    const int cr = (lane >> 4) * 4, cc = lane & 15;
    const int colw = n0 + wv * 16 + cc;        // this lane's output col
    const bool wok = colw < V_;
    const float bias = wok ? fcbias[colw] : 0.f;

    for (int t = 0; t < T_; ++t) {
      if (wv == 0) {
        // single poller wave: gather-poll 64 flags at L3, slow cadence
        const int* fp = flags + lane;
        for (;;) {
          int fl = __hip_atomic_load(fp, __ATOMIC_RELAXED, __HIP_MEMORY_SCOPE_AGENT);
          if (__all(fl >= t + 1)) break;
          __builtin_amdgcn_s_sleep(32);
        }
        __hip_atomic_store(&tready, t + 1, __ATOMIC_RELAXED,
                           __HIP_MEMORY_SCOPE_WORKGROUP);
      } else {
        // LDS spin: block-local, no fabric traffic
        while (__hip_atomic_load(&tready, __ATOMIC_RELAXED,
                                 __HIP_MEMORY_SCOPE_WORKGROUP) < t + 1)
          __builtin_amdgcn_s_sleep(2);
      }
      asm volatile("" ::: "memory");
      // 32x16 tile per wave: A = hs[t] rows (batch), B = Wlds rows wv*16+lr
      const short* Ap = hs + (size_t)t * (B_ * H_) + lr * 512 + ko;
      f32x4 acc0 = {}, acc1 = {};
#pragma unroll
      for (int k = 0; k < 512; k += 32) {
        bf16x8 a0 = *(const bf16x8*)(Ap + k);
        bf16x8 a1 = *(const bf16x8*)(Ap + 16 * 512 + k);
        bf16x8 b  = lds_ld16B(Wlds, wv * 16 + lr, k + ko);
        acc0 = mfma16(a0, b, acc0);
        acc1 = mfma16(a1, b, acc1);
      }
      if (wok) {
#pragma unroll
        for (int j = 0; j < 4; ++j) {
          out[(size_t)(cr + j) * (T_ * V_) + t * V_ + colw]      = acc0[j] + bias;
          out[(size_t)(16 + cr + j) * (T_ * V_) + t * V_ + colw] = acc1[j] + bias;
        }
      }
    }
  }
}

// ---------------- launch ----------------

extern "C" void kernel_launch(void* const* d_in, const int* in_sizes, int n_in,
                              void* d_out, int out_size, void* d_ws, size_t ws_size,
                              hipStream_t stream) {
  const float* features = (const float*)d_in[0];
  const int*   captions = (const int*)d_in[1];
  const float* embed    = (const float*)d_in[3];
  const float* W_ih     = (const float*)d_in[4];
  const float* W_hh     = (const float*)d_in[5];
  const float* b_ih     = (const float*)d_in[6];
  const float* b_hh     = (const float*)d_in[7];
  const float* fc_W     = (const float*)d_in[8];
  const float* fc_b     = (const float*)d_in[9];
  float* out = (float*)d_out;

  char* ws = (char*)d_ws;
  size_t off = 0;
  auto alloc = [&](size_t bytes) -> void* {
    off = (off + 255) & ~(size_t)255;
    void* p = ws + off;
    off += bytes;
    return p;
  };
  int*      flags  = (int*)     alloc(4096);
  short*    wih_bf = (short*)   alloc((size_t)G4 * E_ * 2);
  short*    whh_bf = (short*)   alloc((size_t)G4 * H_ * 2);
  short*    fcw_bf = (short*)   alloc((size_t)V_ * H_ * 2);
  float*    bsum   = (float*)   alloc((size_t)G4 * 4);
  float*    Gx     = (float*)   alloc((size_t)T_ * B_ * G4 * 4);
  short*    xs     = (short*)   alloc((size_t)T_ * B_ * E_ * 2);
  short*    hs     = (short*)   alloc((size_t)T_ * B_ * H_ * 2);

  (void)hipMemsetAsync(flags, 0, 4096, stream);
  prep_kernel<<<2048, 256, 0, stream>>>(W_ih, W_hh, fc_W, b_ih, b_hh,
                                        features, captions, embed,
                                        wih_bf, whh_bf, fcw_bf, bsum, xs);
  gemm_gx_kernel<<<dim3(32, 32), 256, 0, stream>>>(xs, wih_bf, bsum, Gx);
  fused_kernel<<<NTOT, 256, 0, stream>>>(whh_bf, Gx, hs, flags,
                                         fcw_bf, fc_b, out);
}